// Round 5
// baseline (181.207 us; speedup 1.0000x reference)
//
#include <hip/hip_runtime.h>
#include <hip/hip_bf16.h>

#define BB 32
#define CC 192
#define HH 64
#define WW 64
#define OO 192
#define EE 8
#define KTOT (CC*9)      // 1728
#define NSP (HH*WW)      // 4096
#define EWN (OO*CC*9)    // 331776 per expert

typedef __attribute__((ext_vector_type(8))) __bf16 bf16x8;
typedef __attribute__((ext_vector_type(4))) float f32x4;
typedef __attribute__((ext_vector_type(16))) float f32x16;

// async global->LDS, 16B per lane (dest = wave-uniform base + lane*16)
__device__ __forceinline__ void gl_lds16(const void* g, void* l) {
    __builtin_amdgcn_global_load_lds(
        (const __attribute__((address_space(1))) unsigned int*)g,
        (__attribute__((address_space(3))) unsigned int*)l, 16, 0, 0);
}

// ---------------- kernel 1: fused transpose (NCHW f32 -> NHWC bf16) + global avg pool ----
__global__ __launch_bounds__(256) void transpose_pool_kernel(const float* __restrict__ x,
                                                             __bf16* __restrict__ xT,
                                                             float* __restrict__ pooled) {
    const int ct = blockIdx.x, h = blockIdx.y, b = blockIdx.z;
    const int c0 = ct * 64;
    __shared__ float T[64][65];
    const int t = threadIdx.x;
    const int cr = t >> 2, wq = t & 3;
    const float* xr = x + (((size_t)b * CC + c0 + cr) * HH + h) * WW;
    float ps = 0.f;
#pragma unroll
    for (int i = 0; i < 4; ++i) {
        float4 v = *(const float4*)(xr + (wq + i * 4) * 4);
        int wbase = (wq + i * 4) * 4;
        T[cr][wbase + 0] = v.x; T[cr][wbase + 1] = v.y;
        T[cr][wbase + 2] = v.z; T[cr][wbase + 3] = v.w;
        ps += v.x + v.y + v.z + v.w;
    }
    ps += __shfl_down(ps, 2);
    ps += __shfl_down(ps, 1);
    if (wq == 0) atomicAdd(pooled + b * CC + c0 + cr, ps);
    __syncthreads();
#pragma unroll
    for (int i = 0; i < 2; ++i) {
        int u = t + 256 * i;
        int w = u >> 3, ch = u & 7;
        bf16x8 o;
#pragma unroll
        for (int j = 0; j < 8; ++j) o[j] = (__bf16)T[ch * 8 + j][w];
        *(bf16x8*)(xT + (((size_t)b * HH + h) * WW + w) * CC + c0 + ch * 8) = o;
    }
}

// ---------------- kernel 2: mix expert weights -> bf16 (routing computed inline) ----
// dest: wmT[b][o][(kh*3+kw)*192 + c]; src i = (o*192+c)*9 + (kh*3+kw)
__global__ __launch_bounds__(256) void mix_kernel(const float* __restrict__ ew,
                                                  const float* __restrict__ pooled,
                                                  const float* __restrict__ rw,
                                                  const float* __restrict__ rb,
                                                  __bf16* __restrict__ wmT) {
    __shared__ float r[8 * EE];
    __shared__ float es[EE][KTOT];
    const int t = threadIdx.x;
    const int o = blockIdx.x;
    const int b0 = blockIdx.y * 8;
    const size_t base = (size_t)o * KTOT;
#pragma unroll
    for (int e = 0; e < EE; ++e)
        for (int s = t; s < KTOT; s += 256)
            es[e][s] = ew[(size_t)e * EWN + base + s];
    if (t < 64) {
        const int bl = t >> 3, e = t & 7;
        const float* pb = pooled + (b0 + bl) * CC;
        const float* we = rw + e * CC;
        float acc = 0.f;
        for (int c = 0; c < CC; ++c) acc += pb[c] * we[c];
        acc = acc * (1.0f / 4096.0f) + rb[e];
        r[bl * EE + e] = 1.0f / (1.0f + expf(-acc));
    }
    __syncthreads();
    for (int i = 0; i < 7; ++i) {
        int jl = t + 256 * i;
        if (jl >= KTOT) break;
        int c = jl % 192;
        int t9 = jl / 192;
        int s = c * 9 + t9;
        float w[EE];
#pragma unroll
        for (int e = 0; e < EE; ++e) w[e] = es[e][s];
#pragma unroll
        for (int bi = 0; bi < 8; ++bi) {
            float acc = 0.f;
#pragma unroll
            for (int e = 0; e < EE; ++e) acc += r[bi * EE + e] * w[e];
            wmT[(size_t)(b0 + bi) * EWN + base + jl] = (__bf16)acc;
        }
    }
}

// ---------------- kernel 3: NHWC implicit-GEMM conv via 32x32x16 MFMA ----------------
// Block tile: 192(o) x 128(n = 2 h-rows x 64 w), BK=64, 256 threads (4 waves 2Mx2N).
// Per-wave 96x64 = 3x2 fragments of 32x32. LDS 2 x 40 KB -> 2 blocks/CU.
#define A_ELEMS (192*64)
#define B_ELEMS (128*64)
#define BUFE (A_ELEMS + B_ELEMS)   // 20480 bf16 = 40960 B

__global__ __launch_bounds__(256) void conv_kernel(const __bf16* __restrict__ xT,
                                                   const __bf16* __restrict__ wmT,
                                                   const __bf16* __restrict__ zp,
                                                   float* __restrict__ out) {
    extern __shared__ __bf16 smem[];   // 2 * BUFE = 81920 B

    // bijective XCD swizzle: 1024 blocks, each XCD gets 4 consecutive b x 32 h-pairs
    const int gid = blockIdx.x;              // 0..1023
    const int nid = (gid & 7) * 128 + (gid >> 3);
    const int b  = nid >> 5;                 // 0..31
    const int h0 = (nid & 31) * 2;           // 0,2,..,62

    const int t = threadIdx.x;
    const int lane = t & 63;
    const int wv = t >> 6;                   // 0..3
    const int wr = wv >> 1;                  // 0..1 (M half: 96 rows)
    const int wc = wv & 1;                   // 0..1 (N half: one h-row, 64 w)
    const int l31 = lane & 31;
    const int lhi = lane >> 5;               // k-half selector
    const int lrow = lane >> 3;              // 0..7
    const int offB = (((lane & 7) ^ lrow) << 4);   // pre-swizzled source byte offset

    const char* wmb = (const char*)(wmT + (size_t)b * (OO * KTOT));
    const char* xtb = (const char*)(xT + (size_t)b * (HH * WW * CC));
    const char* zpb = (const char*)zp;

    f32x16 acc[3][2];
#pragma unroll
    for (int mi = 0; mi < 3; ++mi)
#pragma unroll
        for (int ni = 0; ni < 2; ++ni)
#pragma unroll
            for (int j = 0; j < 16; ++j) acc[mi][ni][j] = 0.f;

    auto STAGE = [&](int buf, int step) {
        const int t9 = step / 3;
        const int cc = step - t9 * 3;
        const int kh = t9 / 3;
        const int kw = t9 - kh * 3;
        const int c0 = cc * 64;
        __bf16* As = smem + buf * BUFE;
        __bf16* Bs = As + A_ELEMS;
        const size_t kB = (size_t)step * 128;        // byte offset within wm row
        // A: 24 KB = 24 chunks (8 rows x 128 B); this wave: 6
#pragma unroll
        for (int i = 0; i < 6; ++i) {
            const int chunk = wv * 6 + i;
            const char* src = wmb + (size_t)(chunk * 8 + lrow) * (KTOT * 2) + kB + offB;
            gl_lds16(src, (void*)(As + chunk * 512));
        }
        // B: 16 KB = 16 chunks (8 rows x 128 B); this wave: 4
#pragma unroll
        for (int i = 0; i < 4; ++i) {
            const int chunk = wv * 4 + i;
            const int n = chunk * 8 + lrow;          // 0..127
            const int hl = n >> 6;
            const int w = n & 63;
            const int hp = h0 + hl + kh - 1;
            const int wp = w + kw - 1;
            const bool ok = ((unsigned)hp < (unsigned)HH) && ((unsigned)wp < (unsigned)WW);
            const char* src = ok
                ? xtb + ((size_t)(hp * WW + wp) * CC + c0) * 2 + offB
                : zpb + offB;
            gl_lds16(src, (void*)(Bs + chunk * 512));
        }
    };

    STAGE(0, 0);
    for (int step = 0; step < 27; ++step) {
        const int cur = step & 1;
        if (step + 1 < 27) {
            STAGE(cur ^ 1, step + 1);                         // 10 loads in flight for t+1
            asm volatile("s_waitcnt vmcnt(10)" ::: "memory"); // tile t's 10 landed
        } else {
            asm volatile("s_waitcnt vmcnt(0)" ::: "memory");
        }
        __builtin_amdgcn_s_barrier();
        __builtin_amdgcn_sched_barrier(0);

        const __bf16* As = smem + cur * BUFE;
        const __bf16* Bs = As + A_ELEMS;
#pragma unroll
        for (int kci = 0; kci < 4; ++kci) {
            const int kc = (kci + wv) & 3;          // stagger waves across kc phases
            bf16x8 a[3], bbf[2];
#pragma unroll
            for (int mi = 0; mi < 3; ++mi) {
                const int r = wr * 96 + mi * 32 + l31;
                const int col = (kc * 32 + lhi * 16) ^ ((r & 7) << 4);
                a[mi] = *(const bf16x8*)((const char*)As + r * 128 + col);
            }
#pragma unroll
            for (int ni = 0; ni < 2; ++ni) {
                const int r = wc * 64 + ni * 32 + l31;
                const int col = (kc * 32 + lhi * 16) ^ ((r & 7) << 4);
                bbf[ni] = *(const bf16x8*)((const char*)Bs + r * 128 + col);
            }
            __builtin_amdgcn_s_setprio(1);
#pragma unroll
            for (int mi = 0; mi < 3; ++mi)
#pragma unroll
                for (int ni = 0; ni < 2; ++ni)
                    acc[mi][ni] = __builtin_amdgcn_mfma_f32_32x32x16_bf16(
                        a[mi], bbf[ni], acc[mi][ni], 0, 0, 0);
            __builtin_amdgcn_s_setprio(0);
        }
        __builtin_amdgcn_s_barrier();
        __builtin_amdgcn_sched_barrier(0);
    }

    // epilogue: D layout col = lane&31, row = (reg&3) + 8*(reg>>2) + 4*(lane>>5)
    float* ob = out + (size_t)b * OO * NSP + (size_t)(h0 + wc) * WW;
#pragma unroll
    for (int mi = 0; mi < 3; ++mi)
#pragma unroll
        for (int ni = 0; ni < 2; ++ni)
#pragma unroll
            for (int reg = 0; reg < 16; ++reg) {
                const int o = wr * 96 + mi * 32 + (reg & 3) + 8 * (reg >> 2) + 4 * lhi;
                const int w = ni * 32 + l31;
                ob[(size_t)o * NSP + w] = acc[mi][ni][reg];
            }
}

extern "C" void kernel_launch(void* const* d_in, const int* in_sizes, int n_in,
                              void* d_out, int out_size, void* d_ws, size_t ws_size,
                              hipStream_t stream) {
    const float* x  = (const float*)d_in[0];
    const float* ew = (const float*)d_in[1];
    const float* rw = (const float*)d_in[2];
    const float* rb = (const float*)d_in[3];
    float* out = (float*)d_out;

    char* ws = (char*)d_ws;
    float*  pooled  = (float*)(ws + 4096);
    __bf16* zp      = (__bf16*)(ws + 32768);
    __bf16* xT      = (__bf16*)(ws + 65536);                 // 50,331,648 B
    __bf16* wmT     = (__bf16*)(ws + 65536 + 50331648);      // 21,233,664 B

    hipMemsetAsync(pooled, 0, BB * CC * sizeof(float), stream);
    hipMemsetAsync(zp, 0, 1024, stream);

    hipFuncSetAttribute((const void*)conv_kernel,
                        hipFuncAttributeMaxDynamicSharedMemorySize, 2 * BUFE * 2);

    hipLaunchKernelGGL(transpose_pool_kernel, dim3(3, HH, BB), dim3(256), 0, stream,
                       x, xT, pooled);
    hipLaunchKernelGGL(mix_kernel, dim3(OO, 4), dim3(256), 0, stream,
                       ew, pooled, rw, rb, wmT);
    hipLaunchKernelGGL(conv_kernel, dim3(1024), dim3(256), 2 * BUFE * 2, stream,
                       xT, wmT, zp, out);
}

// Round 7
// 170.225 us; speedup vs baseline: 1.0645x; 1.0645x over previous
//
#include <hip/hip_runtime.h>
#include <hip/hip_bf16.h>

#define BB 32
#define CC 192
#define HH 64
#define WW 64
#define OO 192
#define EE 8
#define KTOT (CC*9)      // 1728
#define NSP (HH*WW)      // 4096
#define EWN (OO*CC*9)    // 331776 per expert

typedef __attribute__((ext_vector_type(8))) __bf16 bf16x8;
typedef __attribute__((ext_vector_type(4))) float f32x4;

// async global->LDS, 16B per lane (dest = wave-uniform base + lane*16)
__device__ __forceinline__ void gl_lds16(const void* g, void* l) {
    __builtin_amdgcn_global_load_lds(
        (const __attribute__((address_space(1))) unsigned int*)g,
        (__attribute__((address_space(3))) unsigned int*)l, 16, 0, 0);
}

// ---------------- kernel 1: fused transpose (NCHW f32 -> NHWC bf16) + global avg pool ----
__global__ __launch_bounds__(256) void transpose_pool_kernel(const float* __restrict__ x,
                                                             __bf16* __restrict__ xT,
                                                             float* __restrict__ pooled) {
    const int ct = blockIdx.x, h = blockIdx.y, b = blockIdx.z;
    const int c0 = ct * 64;
    __shared__ float T[64][65];
    const int t = threadIdx.x;
    const int cr = t >> 2, wq = t & 3;
    const float* xr = x + (((size_t)b * CC + c0 + cr) * HH + h) * WW;
    float ps = 0.f;
#pragma unroll
    for (int i = 0; i < 4; ++i) {
        float4 v = *(const float4*)(xr + (wq + i * 4) * 4);
        int wbase = (wq + i * 4) * 4;
        T[cr][wbase + 0] = v.x; T[cr][wbase + 1] = v.y;
        T[cr][wbase + 2] = v.z; T[cr][wbase + 3] = v.w;
        ps += v.x + v.y + v.z + v.w;
    }
    ps += __shfl_down(ps, 2);
    ps += __shfl_down(ps, 1);
    if (wq == 0) atomicAdd(pooled + b * CC + c0 + cr, ps);
    __syncthreads();
#pragma unroll
    for (int i = 0; i < 2; ++i) {
        int u = t + 256 * i;
        int w = u >> 3, ch = u & 7;
        bf16x8 o;
#pragma unroll
        for (int j = 0; j < 8; ++j) o[j] = (__bf16)T[ch * 8 + j][w];
        *(bf16x8*)(xT + (((size_t)b * HH + h) * WW + w) * CC + c0 + ch * 8) = o;
    }
}

// ---------------- kernel 2: mix expert weights -> bf16 (routing computed inline) ----
__global__ __launch_bounds__(256) void mix_kernel(const float* __restrict__ ew,
                                                  const float* __restrict__ pooled,
                                                  const float* __restrict__ rw,
                                                  const float* __restrict__ rb,
                                                  __bf16* __restrict__ wmT) {
    __shared__ float r[8 * EE];
    __shared__ float es[EE][KTOT];
    const int t = threadIdx.x;
    const int o = blockIdx.x;
    const int b0 = blockIdx.y * 8;
    const size_t base = (size_t)o * KTOT;
#pragma unroll
    for (int e = 0; e < EE; ++e)
        for (int s = t; s < KTOT; s += 256)
            es[e][s] = ew[(size_t)e * EWN + base + s];
    if (t < 64) {
        const int bl = t >> 3, e = t & 7;
        const float* pb = pooled + (b0 + bl) * CC;
        const float* we = rw + e * CC;
        float acc = 0.f;
        for (int c = 0; c < CC; ++c) acc += pb[c] * we[c];
        acc = acc * (1.0f / 4096.0f) + rb[e];
        r[bl * EE + e] = 1.0f / (1.0f + expf(-acc));
    }
    __syncthreads();
    for (int i = 0; i < 7; ++i) {
        int jl = t + 256 * i;
        if (jl >= KTOT) break;
        int c = jl % 192;
        int t9 = jl / 192;
        int s = c * 9 + t9;
        float w[EE];
#pragma unroll
        for (int e = 0; e < EE; ++e) w[e] = es[e][s];
#pragma unroll
        for (int bi = 0; bi < 8; ++bi) {
            float acc = 0.f;
#pragma unroll
            for (int e = 0; e < EE; ++e) acc += r[bi * EE + e] * w[e];
            wmT[(size_t)(b0 + bi) * EWN + base + jl] = (__bf16)acc;
        }
    }
}

// ---------------- kernel 3: NHWC implicit-GEMM conv, 2-phase pipelined ----------------
// R3 geometry: 192(o) x 128(n = 2 h-rows x 64 w), BK=64, 512 thr, 8 waves 4Mx2N.
// Per K-step: ph0 {A-stage(t+1) | vmcnt(3) | bar | ds_read kc0 | MFMA} ;
//             ph1 {B-stage(t+1) | ds_read kc1 | MFMA | bar}. Counted vmcnt, never 0 mid-loop.
#define A_ELEMS (192*64)
#define B_ELEMS (128*64)
#define BUFE (A_ELEMS + B_ELEMS)   // 20480 bf16 = 40960 B

__global__ __launch_bounds__(512) void conv_kernel(const __bf16* __restrict__ xT,
                                                   const __bf16* __restrict__ wmT,
                                                   const __bf16* __restrict__ zp,
                                                   float* __restrict__ out) {
    extern __shared__ __bf16 smem[];   // 2 * BUFE = 81920 B

    // bijective XCD swizzle: 1024 blocks; each XCD gets 4 consecutive b x 32 h-pairs
    const int gid = blockIdx.x;              // 0..1023
    const int nid = (gid & 7) * 128 + (gid >> 3);
    const int b  = nid >> 5;                 // 0..31
    const int h0 = (nid & 31) * 2;           // 0,2,..,62

    const int t = threadIdx.x;
    const int lane = t & 63;
    const int wv = t >> 6;                   // 0..7
    const int wr = wv >> 1;                  // 0..3 (M quadrant: 48 rows)
    const int wc = wv & 1;                   // 0..1 (N half: one h-row)
    const int l15 = lane & 15, lch = lane >> 4;
    const int lrow = lane >> 3;              // 0..7
    const int offB = (((lane & 7) ^ lrow) << 4);   // pre-swizzled source byte offset

    const char* wmb = (const char*)(wmT + (size_t)b * (OO * KTOT));
    const char* xtb = (const char*)(xT + (size_t)b * (HH * WW * CC));
    const char* zpb = (const char*)zp;

    f32x4 acc[3][4];
#pragma unroll
    for (int mi = 0; mi < 3; ++mi)
#pragma unroll
        for (int ni = 0; ni < 4; ++ni) acc[mi][ni] = (f32x4){0.f, 0.f, 0.f, 0.f};

    auto STAGE_A = [&](int buf, int step) {
        __bf16* As = smem + buf * BUFE;
        const size_t kB = (size_t)step * 128;
#pragma unroll
        for (int i = 0; i < 3; ++i) {
            const int chunk = wv * 3 + i;
            const char* src = wmb + (size_t)(chunk * 8 + lrow) * (KTOT * 2) + kB + offB;
            gl_lds16(src, (void*)(As + chunk * 512));
        }
    };
    auto STAGE_B = [&](int buf, int step) {
        const int t9 = step / 3;
        const int cc = step - t9 * 3;
        const int kh = t9 / 3;
        const int kw = t9 - kh * 3;
        const int c0 = cc * 64;
        __bf16* Bs = smem + buf * BUFE + A_ELEMS;
#pragma unroll
        for (int i = 0; i < 2; ++i) {
            const int chunk = wv * 2 + i;
            const int n = chunk * 8 + lrow;          // 0..127
            const int hl = n >> 6;
            const int w = n & 63;
            const int hp = h0 + hl + kh - 1;
            const int wp = w + kw - 1;
            const bool ok = ((unsigned)hp < (unsigned)HH) && ((unsigned)wp < (unsigned)WW);
            const char* src = ok
                ? xtb + ((size_t)(hp * WW + wp) * CC + c0) * 2 + offB
                : zpb + offB;
            gl_lds16(src, (void*)(Bs + chunk * 512));
        }
    };

    STAGE_A(0, 0);
    STAGE_B(0, 0);                                    // 5 outstanding
    for (int step = 0; step < 27; ++step) {
        const int cur = step & 1;
        const __bf16* As = smem + cur * BUFE;
        const __bf16* Bs = As + A_ELEMS;

        // ---------- phase 0 ----------
        if (step < 26) {
            STAGE_A(cur ^ 1, step + 1);               // +3 -> 8 outstanding
            asm volatile("s_waitcnt vmcnt(3)" ::: "memory");  // cur's 5 landed
        } else {
            asm volatile("s_waitcnt vmcnt(0)" ::: "memory");
        }
        __builtin_amdgcn_s_barrier();
        __builtin_amdgcn_sched_barrier(0);
        {
            bf16x8 a[3], bbf[4];
#pragma unroll
            for (int mi = 0; mi < 3; ++mi) {
                const int r = wr * 48 + mi * 16 + l15;
                const int col = (lch * 16) ^ ((r & 7) << 4);
                a[mi] = *(const bf16x8*)((const char*)As + r * 128 + col);
            }
#pragma unroll
            for (int ni = 0; ni < 4; ++ni) {
                const int r = wc * 64 + ni * 16 + l15;
                const int col = (lch * 16) ^ ((r & 7) << 4);
                bbf[ni] = *(const bf16x8*)((const char*)Bs + r * 128 + col);
            }
            __builtin_amdgcn_sched_barrier(0);
            __builtin_amdgcn_s_setprio(1);
#pragma unroll
            for (int mi = 0; mi < 3; ++mi)
#pragma unroll
                for (int ni = 0; ni < 4; ++ni)
                    acc[mi][ni] = __builtin_amdgcn_mfma_f32_16x16x32_bf16(
                        a[mi], bbf[ni], acc[mi][ni], 0, 0, 0);
            __builtin_amdgcn_s_setprio(0);
        }
        __builtin_amdgcn_s_barrier();
        __builtin_amdgcn_sched_barrier(0);

        // ---------- phase 1 ----------
        if (step < 26) STAGE_B(cur ^ 1, step + 1);    // +2 -> 5 outstanding
        {
            bf16x8 a[3], bbf[4];
#pragma unroll
            for (int mi = 0; mi < 3; ++mi) {
                const int r = wr * 48 + mi * 16 + l15;
                const int col = (64 + lch * 16) ^ ((r & 7) << 4);
                a[mi] = *(const bf16x8*)((const char*)As + r * 128 + col);
            }
#pragma unroll
            for (int ni = 0; ni < 4; ++ni) {
                const int r = wc * 64 + ni * 16 + l15;
                const int col = (64 + lch * 16) ^ ((r & 7) << 4);
                bbf[ni] = *(const bf16x8*)((const char*)Bs + r * 128 + col);
            }
            __builtin_amdgcn_sched_barrier(0);
            __builtin_amdgcn_s_setprio(1);
#pragma unroll
            for (int mi = 0; mi < 3; ++mi)
#pragma unroll
                for (int ni = 0; ni < 4; ++ni)
                    acc[mi][ni] = __builtin_amdgcn_mfma_f32_16x16x32_bf16(
                        a[mi], bbf[ni], acc[mi][ni], 0, 0, 0);
            __builtin_amdgcn_s_setprio(0);
        }
        __builtin_amdgcn_s_barrier();
        __builtin_amdgcn_sched_barrier(0);
    }

    // epilogue: D layout col = lane&15, row = (lane>>4)*4 + j
    float* ob = out + (size_t)b * OO * NSP + (size_t)(h0 + wc) * WW;
#pragma unroll
    for (int mi = 0; mi < 3; ++mi)
#pragma unroll
        for (int ni = 0; ni < 4; ++ni)
#pragma unroll
            for (int j = 0; j < 4; ++j) {
                const int o = wr * 48 + mi * 16 + lch * 4 + j;
                const int w = ni * 16 + l15;
                ob[(size_t)o * NSP + w] = acc[mi][ni][j];
            }
}

extern "C" void kernel_launch(void* const* d_in, const int* in_sizes, int n_in,
                              void* d_out, int out_size, void* d_ws, size_t ws_size,
                              hipStream_t stream) {
    const float* x  = (const float*)d_in[0];
    const float* ew = (const float*)d_in[1];
    const float* rw = (const float*)d_in[2];
    const float* rb = (const float*)d_in[3];
    float* out = (float*)d_out;

    char* ws = (char*)d_ws;
    float*  pooled  = (float*)(ws + 4096);
    __bf16* zp      = (__bf16*)(ws + 32768);
    __bf16* xT      = (__bf16*)(ws + 65536);                 // 50,331,648 B
    __bf16* wmT     = (__bf16*)(ws + 65536 + 50331648);      // 21,233,664 B

    hipMemsetAsync(pooled, 0, BB * CC * sizeof(float), stream);
    hipMemsetAsync(zp, 0, 1024, stream);

    hipFuncSetAttribute((const void*)conv_kernel,
                        hipFuncAttributeMaxDynamicSharedMemorySize, 2 * BUFE * 2);

    hipLaunchKernelGGL(transpose_pool_kernel, dim3(3, HH, BB), dim3(256), 0, stream,
                       x, xT, pooled);
    hipLaunchKernelGGL(mix_kernel, dim3(OO, 4), dim3(256), 0, stream,
                       ew, pooled, rw, rb, wmT);
    hipLaunchKernelGGL(conv_kernel, dim3(1024), dim3(512), 2 * BUFE * 2, stream,
                       xT, wmT, zp, out);
}